// Round 2
// baseline (11550.666 us; speedup 1.0000x reference)
//
#include <hip/hip_runtime.h>

// SNN with synaptic current + recurrent drive, B=64 T=256 F=1024, fp32.
//
// Grid = 256 WGs = 64 j-slices (16 output neurons) x 4 batch-groups (16 rows),
// persistent, one WG/CU. Each WG holds its W column-slice in LDS as 4 signed
// base-512 digits (each in [-256,255], exact in bf16). spk@W.T is then 4 bf16
// MFMAs per K-chunk whose fp32 accumulations are EXACT (all partial sums are
// integers < 2^24). Limbs recombine in fp64 (exact). syn/mem state is fp64.
// => trajectory matches the exact-arithmetic recurrence to ~1e-10/step, which
// tracks the numpy reference through the chaotic spike dynamics.
//
// Per step, WGs of a batch-group exchange spike bits (16 rows x 1024 bits =
// 2KB) via global memory agent-scope atomics + per-(t,bg) release counters.
// Full-history bitmap (2MB ws) avoids WAR across steps; counters memset per
// launch (graph-replay safe).

#define NT 512

typedef __bf16 bf16x8 __attribute__((ext_vector_type(8)));
typedef float f32x4 __attribute__((ext_vector_type(4)));
typedef int i32x4 __attribute__((ext_vector_type(4)));

static __device__ __forceinline__ unsigned short f2bf(float v) {
    union { float f; unsigned int u; } a; a.f = v;
    unsigned int u = a.u;
    u += 0x7fffu + ((u >> 16) & 1u);   // RNE
    return (unsigned short)(u >> 16);
}

// 4 signed base-512 digits of round(w * 2^36); |w| <= ~0.17 so it fits.
static __device__ __forceinline__ void decomp512(float w, int* d) {
    long long v = llround((double)w * 68719476736.0);  // 2^36
    #pragma unroll
    for (int i = 0; i < 4; ++i) {
        int r = (int)(v & 511);
        if (r >= 256) r -= 512;
        d[i] = r;
        v = (v - (long long)r) >> 9;
    }
}

__launch_bounds__(NT, 1)
__global__ void snn_persist_kernel(const float* __restrict__ x,
                                   const float* __restrict__ W,
                                   const float* __restrict__ bias,
                                   float* __restrict__ out,
                                   unsigned int* __restrict__ cnt,
                                   unsigned int* __restrict__ gbm)
{
    constexpr int T = 256, F = 1024;
    const int bid = blockIdx.x;
    const int js  = bid & 63;   // j-slice: output cols js*16 .. js*16+15
    const int bg  = bid >> 6;   // batch group: rows bg*16 .. bg*16+15
    const int tid = threadIdx.x;
    const int lane = tid & 63;
    const int wv   = tid >> 6;  // wave id 0..7

    // W digit slices, MFMA B-operand order: [kc 0..31][lane 0..63][8 bf16]
    __shared__ __align__(16) unsigned int wd0[32*64*4];
    __shared__ __align__(16) unsigned int wd1[32*64*4];
    __shared__ __align__(16) unsigned int wd2[32*64*4];
    __shared__ __align__(16) unsigned int wd3[32*64*4];
    __shared__ __align__(16) unsigned int rawbm[512];  // [js2 0..63][8 uints]
    __shared__ double partD[8*256];                    // per-wave partial h
    __shared__ unsigned long long bal[4];

    // ---- init: load W slice, 4-digit split, store in fragment order ----
    // B-frag: lane l supplies B[k=(l>>4)*8+i][n=l&15]; global W[js*16+n][kc*32+(l>>4)*8+i]
    for (int it = 0; it < 4; ++it) {
        int s = tid + NT*it;            // slot 0..2047 = (kc,l)
        int kc = s >> 6, l = s & 63;
        int n = l & 15, q = l >> 4;
        int f0 = kc*32 + q*8;
        const float* wr = W + (size_t)(js*16 + n)*F + f0;
        float e[8];
        *(float4*)&e[0] = *(const float4*)(wr);
        *(float4*)&e[4] = *(const float4*)(wr + 4);
        unsigned int pk0[4], pk1[4], pk2[4], pk3[4];
        #pragma unroll
        for (int i = 0; i < 4; ++i) {
            int da[4], db[4];
            decomp512(e[2*i],   da);
            decomp512(e[2*i+1], db);
            pk0[i] = (unsigned int)f2bf((float)da[0]) | ((unsigned int)f2bf((float)db[0]) << 16);
            pk1[i] = (unsigned int)f2bf((float)da[1]) | ((unsigned int)f2bf((float)db[1]) << 16);
            pk2[i] = (unsigned int)f2bf((float)da[2]) | ((unsigned int)f2bf((float)db[2]) << 16);
            pk3[i] = (unsigned int)f2bf((float)da[3]) | ((unsigned int)f2bf((float)db[3]) << 16);
        }
        #pragma unroll
        for (int i = 0; i < 4; ++i) {
            wd0[s*4+i] = pk0[i]; wd1[s*4+i] = pk1[i];
            wd2[s*4+i] = pk2[i]; wd3[s*4+i] = pk3[i];
        }
    }

    // state mapping for tid<256, matching MFMA C layout after LDS reduce:
    // lane = tid&63, r = tid>>6 ; row b = (lane>>4)*4 + r ; col j = lane&15
    const int brow = ((tid >> 4) & 3)*4 + (tid >> 6);
    const int jcol = tid & 15;
    const int bglob = bg*16 + brow;
    const double bj = (double)bias[js*16 + jcol];
    const size_t obase = (size_t)bglob*T*F + js*16 + jcol;
    float* outspk = out;
    float* outmem = out + (size_t)64*T*F;

    double syn = 0.0, mem = 0.0, rst = 0.0;
    float spkf = 0.0f;

    __syncthreads();

    for (int t = 0; t < T; ++t) {
        double h = 0.0;
        if (t > 0) {
            // wait for all 64 producers of this batch-group at step t-1
            if (tid == 0) {
                const unsigned int* c = cnt + ((t-1)*4 + bg)*16;
                while (__hip_atomic_load(c, __ATOMIC_ACQUIRE, __HIP_MEMORY_SCOPE_AGENT) < 64u)
                    __builtin_amdgcn_s_sleep(8);
            }
            __syncthreads();
            // fetch 2KB spike bitmap (coherence-point loads)
            {
                const unsigned int* src = gbm + ((size_t)((t-1)*4 + bg)*64 + (tid>>3))*8 + (tid&7);
                rawbm[tid] = __hip_atomic_load(src, __ATOMIC_RELAXED, __HIP_MEMORY_SCOPE_AGENT);
            }
            __syncthreads();
            // MFMA: C[b][j] = sum_f spk[b,f]*Wq[j,f], K split over 8 waves,
            // 4 digit-limbs accumulated separately (all-integer fp32, exact)
            f32x4 ac0 = {0.f,0.f,0.f,0.f}, ac1 = ac0, ac2 = ac0, ac3 = ac0;
            const int q = lane >> 4, r15 = lane & 15;
            const unsigned short* rbm16 = (const unsigned short*)rawbm;
            #pragma unroll
            for (int c4 = 0; c4 < 4; ++c4) {
                int kc = wv*4 + c4;
                // A-frag: lane supplies A[row=r15][k=q*8+i] -> f = kc*32+q*8+i
                int js2 = 2*kc + (q >> 1);
                unsigned int us = rbm16[js2*16 + r15];
                unsigned int byt = (us >> ((q & 1)*8)) & 0xFFu;
                unsigned int d0 = ((byt&1u)  ?0x3F80u:0u) | ((byt&2u)  ?0x3F800000u:0u);
                unsigned int d1 = ((byt&4u)  ?0x3F80u:0u) | ((byt&8u)  ?0x3F800000u:0u);
                unsigned int d2 = ((byt&16u) ?0x3F80u:0u) | ((byt&32u) ?0x3F800000u:0u);
                unsigned int d3 = ((byt&64u) ?0x3F80u:0u) | ((byt&128u)?0x3F800000u:0u);
                i32x4 ai = {(int)d0, (int)d1, (int)d2, (int)d3};
                bf16x8 a = __builtin_bit_cast(bf16x8, ai);
                size_t fo = (size_t)(kc*64 + lane)*4;
                bf16x8 b0 = *(const bf16x8*)(wd0 + fo);
                bf16x8 b1 = *(const bf16x8*)(wd1 + fo);
                bf16x8 b2 = *(const bf16x8*)(wd2 + fo);
                bf16x8 b3 = *(const bf16x8*)(wd3 + fo);
                ac0 = __builtin_amdgcn_mfma_f32_16x16x32_bf16(a, b0, ac0, 0, 0, 0);
                ac1 = __builtin_amdgcn_mfma_f32_16x16x32_bf16(a, b1, ac1, 0, 0, 0);
                ac2 = __builtin_amdgcn_mfma_f32_16x16x32_bf16(a, b2, ac2, 0, 0, 0);
                ac3 = __builtin_amdgcn_mfma_f32_16x16x32_bf16(a, b3, ac3, 0, 0, 0);
            }
            // recombine limbs in fp64 (exact): weight of limb i = 2^(9i-36)
            const double c0 = 1.0/68719476736.0;   // 2^-36
            const double c1 = 1.0/134217728.0;     // 2^-27
            const double c2 = 1.0/262144.0;        // 2^-18
            const double c3 = 1.0/512.0;           // 2^-9
            #pragma unroll
            for (int r = 0; r < 4; ++r)
                partD[wv*256 + r*64 + lane] =
                    (double)ac0[r]*c0 + (double)ac1[r]*c1 +
                    (double)ac2[r]*c2 + (double)ac3[r]*c3;
            __syncthreads();
            if (tid < 256) {
                #pragma unroll
                for (int w = 0; w < 8; ++w) h += partD[w*256 + tid];
            }
        }
        // elementwise update in fp64 (reset == spk_prev: both are mem_prev>1)
        if (tid < 256) {
            double xd = (double)x[obase + (size_t)t*F];
            syn = 0.8*syn + xd + h + bj;
            mem = 0.9*mem + syn - rst;
            bool sp = (mem > 1.0);
            spkf = sp ? 1.0f : 0.0f;
            rst  = sp ? 1.0  : 0.0;
            outspk[obase + (size_t)t*F] = spkf;
            outmem[obase + (size_t)t*F] = (float)mem;
            unsigned long long m = __ballot(sp);
            if (lane == 0) bal[wv] = m;
        }
        __syncthreads();
        // post own 16 rows x 16 bits: [t][bg][js][8 uints], uint w = rows 2w,2w+1
        if (tid < 8) {
            int row0 = 2*tid, row1 = 2*tid + 1;
            unsigned int u0 = (unsigned int)((bal[row0 & 3] >> (16*(row0 >> 2))) & 0xFFFFull);
            unsigned int u1 = (unsigned int)((bal[row1 & 3] >> (16*(row1 >> 2))) & 0xFFFFull);
            unsigned int* dst = gbm + ((size_t)(t*4 + bg)*64 + js)*8 + tid;
            __hip_atomic_store(dst, u0 | (u1 << 16), __ATOMIC_RELAXED, __HIP_MEMORY_SCOPE_AGENT);
        }
        __threadfence();
        __syncthreads();
        if (tid == 0) {
            unsigned int* c = cnt + (t*4 + bg)*16;
            __hip_atomic_fetch_add(c, 1u, __ATOMIC_RELEASE, __HIP_MEMORY_SCOPE_AGENT);
        }
    }
}

extern "C" void kernel_launch(void* const* d_in, const int* in_sizes, int n_in,
                              void* d_out, int out_size, void* d_ws, size_t ws_size,
                              hipStream_t stream) {
    const float* x    = (const float*)d_in[0];
    const float* W    = (const float*)d_in[1];
    const float* bias = (const float*)d_in[2];
    float* out = (float*)d_out;

    // ws: [0,64KB) per-(t,bg) release counters (64B stride); [64KB, 64KB+2MB) spike bitmaps
    unsigned int* cnt = (unsigned int*)d_ws;
    unsigned int* gbm = (unsigned int*)((char*)d_ws + 65536);

    hipMemsetAsync(d_ws, 0, 65536, stream);  // counters must start at 0 every launch
    hipLaunchKernelGGL(snn_persist_kernel, dim3(256), dim3(512), 0, stream,
                       x, W, bias, out, cnt, gbm);
}

// Round 3
// 564.282 us; speedup vs baseline: 20.4697x; 20.4697x over previous
//
#include <hip/hip_runtime.h>

// SNN with synaptic current + recurrent drive, B=64 T=256 F=1024, fp32.
//
// Grid = 256 WGs (1/CU) = 64 j-slices (16 output neurons) x 4 batch-groups
// (16 rows), persistent. W column-slice lives in LDS as 4 signed base-512
// digits (exact in bf16); spk@W.T = 4 bf16 MFMAs per K-chunk with EXACT
// integer fp32 accumulation; limbs recombine in fp64; syn/mem state fp64.
//
// Cross-WG spike exchange is a FENCE-FREE tagged-word protocol: each 32-bit
// word = ((t+1)<<16) | 16 spike bits, published with relaxed agent-scope
// (sc1) stores. A 4B store is atomic, so data+tag arrive together — no
// release/acquire, no threadfence, no L2 writebacks (the 45us/step cost of
// the previous counter+fence protocol). Consumers poll their own 512B slice
// per-wave with relaxed sc1 loads until all tags match. 4-deep slot ring
// (64KB ws, memset per launch): a consumer seeing tag t from all producers
// proves everyone finished step t-1, hence retired reads of step t-4 data.

#define NT 512

typedef __bf16 bf16x8 __attribute__((ext_vector_type(8)));
typedef float f32x4 __attribute__((ext_vector_type(4)));
typedef int i32x4 __attribute__((ext_vector_type(4)));

static __device__ __forceinline__ unsigned short f2bf(float v) {
    union { float f; unsigned int u; } a; a.f = v;
    unsigned int u = a.u;
    u += 0x7fffu + ((u >> 16) & 1u);   // RNE
    return (unsigned short)(u >> 16);
}

// 4 signed base-512 digits of round(w * 2^36); |w| <= ~0.2 so it fits.
static __device__ __forceinline__ void decomp512(float w, int* d) {
    long long v = llround((double)w * 68719476736.0);  // 2^36
    #pragma unroll
    for (int i = 0; i < 4; ++i) {
        int r = (int)(v & 511);
        if (r >= 256) r -= 512;
        d[i] = r;
        v = (v - (long long)r) >> 9;
    }
}

__launch_bounds__(NT, 1)
__global__ void snn_persist_kernel(const float* __restrict__ x,
                                   const float* __restrict__ W,
                                   const float* __restrict__ bias,
                                   float* __restrict__ out,
                                   unsigned int* __restrict__ gbm)
{
    constexpr int T = 256, F = 1024;
    const int bid = blockIdx.x;
    const int js  = bid & 63;   // j-slice: output cols js*16 .. js*16+15
    const int bg  = bid >> 6;   // batch group: rows bg*16 .. bg*16+15
    const int tid = threadIdx.x;
    const int lane = tid & 63;
    const int wv   = tid >> 6;  // wave id 0..7

    // W digit slices, MFMA B-operand order: [kc 0..31][lane 0..63][8 bf16]
    __shared__ __align__(16) unsigned int wd0[32*64*4];
    __shared__ __align__(16) unsigned int wd1[32*64*4];
    __shared__ __align__(16) unsigned int wd2[32*64*4];
    __shared__ __align__(16) unsigned int wd3[32*64*4];
    __shared__ unsigned short wbm[8][128];   // per-wave bitmap slice
    __shared__ double partD[8*256];          // per-wave partial h

    // ---- init: load W slice, 4-digit split, store in fragment order ----
    // B-frag: lane l supplies B[k=(l>>4)*8+i][n=l&15]; global W[js*16+n][kc*32+(l>>4)*8+i]
    for (int it = 0; it < 4; ++it) {
        int s = tid + NT*it;            // slot 0..2047 = (kc,l)
        int kc = s >> 6, l = s & 63;
        int n = l & 15, q = l >> 4;
        int f0 = kc*32 + q*8;
        const float* wr = W + (size_t)(js*16 + n)*F + f0;
        float e[8];
        *(float4*)&e[0] = *(const float4*)(wr);
        *(float4*)&e[4] = *(const float4*)(wr + 4);
        unsigned int pk0[4], pk1[4], pk2[4], pk3[4];
        #pragma unroll
        for (int i = 0; i < 4; ++i) {
            int da[4], db[4];
            decomp512(e[2*i],   da);
            decomp512(e[2*i+1], db);
            pk0[i] = (unsigned int)f2bf((float)da[0]) | ((unsigned int)f2bf((float)db[0]) << 16);
            pk1[i] = (unsigned int)f2bf((float)da[1]) | ((unsigned int)f2bf((float)db[1]) << 16);
            pk2[i] = (unsigned int)f2bf((float)da[2]) | ((unsigned int)f2bf((float)db[2]) << 16);
            pk3[i] = (unsigned int)f2bf((float)da[3]) | ((unsigned int)f2bf((float)db[3]) << 16);
        }
        #pragma unroll
        for (int i = 0; i < 4; ++i) {
            wd0[s*4+i] = pk0[i]; wd1[s*4+i] = pk1[i];
            wd2[s*4+i] = pk2[i]; wd3[s*4+i] = pk3[i];
        }
    }

    // state mapping for tid<256, matching MFMA C layout after LDS reduce:
    // lane = tid&63, rr = tid>>6 ; row b = ((lane>>4)&3)*4 + rr ; col j = lane&15
    const int brow = ((tid >> 4) & 3)*4 + (tid >> 6);
    const int jcol = tid & 15;
    const int bglob = bg*16 + brow;
    const double bj = (double)bias[js*16 + jcol];
    const size_t obase = (size_t)bglob*T*F + js*16 + jcol;
    float* outspk = out;
    float* outmem = out + (size_t)64*T*F;

    double syn = 0.0, mem = 0.0, rst = 0.0;

    __syncthreads();

    const int q = lane >> 4, r15 = lane & 15;

    for (int t = 0; t < T; ++t) {
        // prefetch x early (latency hides under poll + MFMA)
        float xv = 0.f;
        if (tid < 256) xv = x[obase + (size_t)t*F];

        double h = 0.0;
        if (t > 0) {
            // poll own 512B slice of previous step's tagged bitmap (relaxed sc1)
            const unsigned int tg = (unsigned int)t;   // tag of step t-1 data
            const unsigned int* slot = gbm + (size_t)(((t-1) & 3)*4 + bg)*1024;
            const unsigned int* p0 = slot + wv*128 + lane;
            const unsigned int* p1 = p0 + 64;
            unsigned int v0, v1;
            do {
                v0 = __hip_atomic_load(p0, __ATOMIC_RELAXED, __HIP_MEMORY_SCOPE_AGENT);
                v1 = __hip_atomic_load(p1, __ATOMIC_RELAXED, __HIP_MEMORY_SCOPE_AGENT);
            } while (__any(((v0 >> 16) != tg) | ((v1 >> 16) != tg)));
            // stash data halves in own wave's LDS region (no barrier needed)
            wbm[wv][lane]      = (unsigned short)v0;
            wbm[wv][64 + lane] = (unsigned short)v1;

            // MFMA: C[b][j] = sum_f spk[b,f]*Wq[j,f], K split over 8 waves,
            // 4 digit-limbs accumulated separately (all-integer fp32, exact)
            f32x4 ac0 = {0.f,0.f,0.f,0.f}, ac1 = ac0, ac2 = ac0, ac3 = ac0;
            #pragma unroll
            for (int c4 = 0; c4 < 4; ++c4) {
                int kc = wv*4 + c4;
                // A-frag: lane supplies A[row=r15][k=q*8+i] -> f = kc*32+q*8+i
                unsigned int us = wbm[wv][(2*c4 + (q >> 1))*16 + r15];
                unsigned int byt = (us >> ((q & 1)*8)) & 0xFFu;
                unsigned int d0 = ((byt&1u)  ?0x3F80u:0u) | ((byt&2u)  ?0x3F800000u:0u);
                unsigned int d1 = ((byt&4u)  ?0x3F80u:0u) | ((byt&8u)  ?0x3F800000u:0u);
                unsigned int d2 = ((byt&16u) ?0x3F80u:0u) | ((byt&32u) ?0x3F800000u:0u);
                unsigned int d3 = ((byt&64u) ?0x3F80u:0u) | ((byt&128u)?0x3F800000u:0u);
                i32x4 ai = {(int)d0, (int)d1, (int)d2, (int)d3};
                bf16x8 a = __builtin_bit_cast(bf16x8, ai);
                size_t fo = (size_t)(kc*64 + lane)*4;
                bf16x8 b0 = *(const bf16x8*)(wd0 + fo);
                bf16x8 b1 = *(const bf16x8*)(wd1 + fo);
                bf16x8 b2 = *(const bf16x8*)(wd2 + fo);
                bf16x8 b3 = *(const bf16x8*)(wd3 + fo);
                ac0 = __builtin_amdgcn_mfma_f32_16x16x32_bf16(a, b0, ac0, 0, 0, 0);
                ac1 = __builtin_amdgcn_mfma_f32_16x16x32_bf16(a, b1, ac1, 0, 0, 0);
                ac2 = __builtin_amdgcn_mfma_f32_16x16x32_bf16(a, b2, ac2, 0, 0, 0);
                ac3 = __builtin_amdgcn_mfma_f32_16x16x32_bf16(a, b3, ac3, 0, 0, 0);
            }
            // recombine limbs in fp64 (exact): weight of limb i = 2^(9i-36)
            const double c0 = 1.0/68719476736.0;   // 2^-36
            const double c1 = 1.0/134217728.0;     // 2^-27
            const double c2 = 1.0/262144.0;        // 2^-18
            const double c3 = 1.0/512.0;           // 2^-9
            #pragma unroll
            for (int r = 0; r < 4; ++r)
                partD[wv*256 + r*64 + lane] =
                    (double)ac0[r]*c0 + (double)ac1[r]*c1 +
                    (double)ac2[r]*c2 + (double)ac3[r]*c3;
            __syncthreads();   // B1: partD complete (uniform: t is uniform)
            if (tid < 256) {
                #pragma unroll
                for (int w = 0; w < 8; ++w) h += partD[w*256 + tid];
            }
        }
        // elementwise update in fp64 (reset == spk_prev: both are mem_prev>1)
        if (tid < 256) {
            syn = 0.8*syn + (double)xv + h + bj;
            mem = 0.9*mem + syn - rst;
            bool sp = (mem > 1.0);
            unsigned long long m = __ballot(sp);
            // publish own rows' tagged words FIRST (critical path):
            // row r = 4g + wv (g = lane>>4), word g = bits [16g,16g+16) of m
            if ((lane & 15) == 0) {
                int g = lane >> 4;
                unsigned int word = (unsigned int)((m >> (16*g)) & 0xFFFFull);
                unsigned int val = (((unsigned int)(t + 1)) << 16) | word;
                unsigned int* dst = gbm + (size_t)((t & 3)*4 + bg)*1024 + js*16 + (4*g + wv);
                __hip_atomic_store(dst, val, __ATOMIC_RELAXED, __HIP_MEMORY_SCOPE_AGENT);
            }
            rst = sp ? 1.0 : 0.0;
            outspk[obase + (size_t)t*F] = sp ? 1.0f : 0.0f;
            outmem[obase + (size_t)t*F] = (float)mem;
        }
        __syncthreads();   // B2: protects partD WAR (writes of t+1 vs reads of t)
    }
}

extern "C" void kernel_launch(void* const* d_in, const int* in_sizes, int n_in,
                              void* d_out, int out_size, void* d_ws, size_t ws_size,
                              hipStream_t stream) {
    const float* x    = (const float*)d_in[0];
    const float* W    = (const float*)d_in[1];
    const float* bias = (const float*)d_in[2];
    float* out = (float*)d_out;

    // ws: 4-slot ring of tagged bitmaps: [slot 0..3][bg 0..3][1024 uints] = 64KB
    unsigned int* gbm = (unsigned int*)d_ws;

    hipMemsetAsync(d_ws, 0, 65536, stream);  // clear tags every launch (replay-safe)
    hipLaunchKernelGGL(snn_persist_kernel, dim3(256), dim3(512), 0, stream,
                       x, W, bias, out, gbm);
}